// Round 9
// baseline (250.818 us; speedup 1.0000x reference)
//
#include <hip/hip_runtime.h>

constexpr int N_DOCS = 4096;
constexpr int N_QS   = 8192;
constexpr int BLOCK  = 256;                      // 4 waves per block
constexpr int SPLITS = 2;                        // waves per row
constexpr int N_PART = N_DOCS * SPLITS;          // 8192 partials
constexpr int GRID   = N_PART / (BLOCK / 64);    // 2048 blocks -> 32 waves/CU
constexpr int HALF_VECS = (N_QS / SPLITS) / 4;   // 1024 fx4 per half-row
constexpr int VECS_PER_LANE = HALF_VECS / 64;    // 16 fx4 per lane
constexpr int CHUNK = 4;                         // keep VGPRs <= 64 (8 waves/SIMD)
constexpr int N_CHUNKS = VECS_PER_LANE / CHUNK;  // 4 chunks

typedef float fx4 __attribute__((ext_vector_type(4)));
typedef int   ix4 __attribute__((ext_vector_type(4)));

// R8 post-mortem: three different structures all plateau at 3.6 TB/s reads
// while harness writes hit 6.9 TB/s -> reads are latency*concurrency bound
// (writes are fire-and-forget). All nt-regime rounds ran 16 waves/CU.
// This round: 2 waves per row -> 32 waves/CU (launch_bounds(256,8) forces
// VGPR<=64), CHUNK=4. Doubling requesters tests the concurrency axis.
__global__ __launch_bounds__(BLOCK, 8) void row_reduce_kernel(
    const fx4* __restrict__ cos4,
    const ix4* __restrict__ mask4,
    float4* __restrict__ partial)     // per half-row: (s_mc, s_nt, cnt, 0)
{
    const int tid  = threadIdx.x;
    const int lane = tid & 63;
    const int part = blockIdx.x * (BLOCK / 64) + (tid >> 6);  // 0..8191
    // half-row 'part': row = part/2, half = part%2
    const long base = (long)part * HALF_VECS + lane;          // contiguous halves

    float s_mc = 0.f, s_nt = 0.f;
    int   icnt = 0;

#pragma unroll
    for (int ch = 0; ch < N_CHUNKS; ++ch) {
        fx4 c[CHUNK];
        ix4 m[CHUNK];
#pragma unroll
        for (int v = 0; v < CHUNK; ++v) {
            const long idx = base + (long)(ch * CHUNK + v) * 64;  // coalesced
            c[v] = __builtin_nontemporal_load(&cos4[idx]);
            m[v] = __builtin_nontemporal_load(&mask4[idx]);
        }
#pragma unroll
        for (int v = 0; v < CHUNK; ++v) {
            s_mc += (m[v].x != 0) ? c[v].x : 0.f;
            s_mc += (m[v].y != 0) ? c[v].y : 0.f;
            s_mc += (m[v].z != 0) ? c[v].z : 0.f;
            s_mc += (m[v].w != 0) ? c[v].w : 0.f;

            s_nt += (m[v].x != 0) ? 0.f : fmaxf(c[v].x, 0.f);
            s_nt += (m[v].y != 0) ? 0.f : fmaxf(c[v].y, 0.f);
            s_nt += (m[v].z != 0) ? 0.f : fmaxf(c[v].z, 0.f);
            s_nt += (m[v].w != 0) ? 0.f : fmaxf(c[v].w, 0.f);

            icnt += m[v].x + m[v].y + m[v].z + m[v].w;  // mask values are 0/1
        }
    }

    float cf = (float)icnt;
#pragma unroll
    for (int off = 32; off > 0; off >>= 1) {
        s_mc += __shfl_down(s_mc, off);
        s_nt += __shfl_down(s_nt, off);
        cf   += __shfl_down(cf,   off);
    }

    if (lane == 0)
        partial[part] = make_float4(s_mc, s_nt, cf, 0.f);
}

// Combine half-row partials, divide per row, mean over rows.
__global__ __launch_bounds__(1024) void final_reduce_kernel(
    const float4* __restrict__ partial,
    float* __restrict__ out)
{
    const int tid = threadIdx.x;
    float a = 0.f, b = 0.f;
#pragma unroll
    for (int r = tid; r < N_DOCS; r += 1024) {
        float4 p0 = partial[2 * r];
        float4 p1 = partial[2 * r + 1];
        float mc = p0.x + p1.x;
        float nt = p0.y + p1.y;
        float ct = p0.z + p1.z;
        a += (ct - mc) / ct;                    // sum m*(1-c) / cnt_t
        b += nt / ((float)N_QS - ct);           // relu-sum / cnt_nt
    }
#pragma unroll
    for (int off = 32; off > 0; off >>= 1) {
        a += __shfl_down(a, off);
        b += __shfl_down(b, off);
    }
    __shared__ float sa[16], sb[16];
    const int wave = tid >> 6;
    const int lane = tid & 63;
    if (lane == 0) { sa[wave] = a; sb[wave] = b; }
    __syncthreads();
    if (tid == 0) {
        float ta = 0.f, tb = 0.f;
#pragma unroll
        for (int w = 0; w < 16; ++w) { ta += sa[w]; tb += sb[w]; }
        float loss_tgt    = ta / (float)N_DOCS;
        float loss_nontgt = tb / (float)N_DOCS;
        out[0] = (loss_tgt + loss_nontgt) * 0.5f;  // loss
        out[1] = loss_tgt;                          // loss_tgt
        out[2] = loss_nontgt;                       // loss_nontgt
    }
}

extern "C" void kernel_launch(void* const* d_in, const int* in_sizes, int n_in,
                              void* d_out, int out_size, void* d_ws, size_t ws_size,
                              hipStream_t stream) {
    const fx4* cos4  = (const fx4*)d_in[0];   // cos_pred fp32 [4096,8192]
    const ix4* mask4 = (const ix4*)d_in[1];   // mask_gt  int32 [4096,8192]
    float4* partial = (float4*)d_ws;          // 8192 * 16 B = 128 KiB scratch
    float*  out     = (float*)d_out;          // 3 fp32 scalars

    row_reduce_kernel<<<GRID, BLOCK, 0, stream>>>(cos4, mask4, partial);
    final_reduce_kernel<<<1, 1024, 0, stream>>>(partial, out);
}